// Round 2
// 889.972 us; speedup vs baseline: 1.0306x; 1.0306x over previous
//
#include <hip/hip_runtime.h>
#include <hip/hip_bf16.h>

// ---------------- problem constants ----------------
#define Bz   32
#define Nn_  577
#define Np   640                    // 577 padded to 5*128
#define Cc   768
#define Hh   3072
#define Mrows (Bz * Nn_)            // 18464
#define OUT_X (Mrows * Cc)          // 14,180,352 floats
#define SCALE 0.03608439182435161f  // 768^-0.5

typedef unsigned short ushort_t;
typedef short short8 __attribute__((ext_vector_type(8)));
typedef float f32x4 __attribute__((ext_vector_type(4)));

__device__ __forceinline__ ushort_t f2b(float f) {
    __hip_bfloat16 h = __float2bfloat16(f);
    return *reinterpret_cast<ushort_t*>(&h);
}

// ---------------- async global->LDS (16B per lane) ----------------
__device__ __forceinline__ void gl16(const ushort_t* g, ushort_t* l) {
    __builtin_amdgcn_global_load_lds(
        (const __attribute__((address_space(1))) void*)g,
        (__attribute__((address_space(3))) void*)l, 16, 0, 0);
}

// ---------------- block reduction helpers (256-thread blocks) ----------------
__device__ __forceinline__ float bsum(float v, float* sm) {
    #pragma unroll
    for (int o = 32; o > 0; o >>= 1) v += __shfl_down(v, o, 64);
    int lane = threadIdx.x & 63, wid = threadIdx.x >> 6;
    if (lane == 0) sm[wid] = v;
    __syncthreads();
    float r = sm[0] + sm[1] + sm[2] + sm[3];
    __syncthreads();
    return r;
}
__device__ __forceinline__ float bmax(float v, float* sm) {
    #pragma unroll
    for (int o = 32; o > 0; o >>= 1) v = fmaxf(v, __shfl_down(v, o, 64));
    int lane = threadIdx.x & 63, wid = threadIdx.x >> 6;
    if (lane == 0) sm[wid] = v;
    __syncthreads();
    float r = fmaxf(fmaxf(sm[0], sm[1]), fmaxf(sm[2], sm[3]));
    __syncthreads();
    return r;
}

// ---------------- fp32 -> bf16 convert ----------------
__global__ void cvt_kernel(const float* __restrict__ in, ushort_t* __restrict__ out, int n) {
    int i = blockIdx.x * 256 + threadIdx.x;
    if (i < n) out[i] = f2b(in[i]);
}

// ---------------- LayerNorm: fp32 in, bf16 out ----------------
__global__ void ln_bf16(const float* __restrict__ x, const float* __restrict__ w,
                        const float* __restrict__ b, ushort_t* __restrict__ out) {
    __shared__ float sm[8];
    long long row = blockIdx.x;
    const float* xr = x + row * Cc;
    float v[3]; float s = 0.f;
    #pragma unroll
    for (int i = 0; i < 3; ++i) { v[i] = xr[threadIdx.x + i * 256]; s += v[i]; }
    float mu = bsum(s, sm) * (1.f / (float)Cc);
    float sq = 0.f;
    #pragma unroll
    for (int i = 0; i < 3; ++i) { float d = v[i] - mu; sq += d * d; }
    float var = bsum(sq, sm + 4) * (1.f / (float)Cc);
    float inv = rsqrtf(var + 1e-5f);
    ushort_t* orow = out + row * Cc;
    #pragma unroll
    for (int i = 0; i < 3; ++i) {
        int c = threadIdx.x + i * 256;
        orow[c] = f2b((v[i] - mu) * inv * w[c] + b[c]);
    }
}

// ---------------- softmax: fp32 Sf (ld 640, 577 valid) -> bf16 Sb (zero-padded) + tok ----------------
__global__ void softmax_bf16(const float* __restrict__ Sf, ushort_t* __restrict__ Sb,
                             float* __restrict__ tok) {
    __shared__ float sm[8];
    long long row = blockIdx.x;
    int b_l = (int)(row / Nn_), r = (int)(row - (long long)b_l * Nn_);
    const float* src = Sf + row * Np;
    ushort_t* dst = Sb + row * Np;
    float v[3]; float mx = -1e30f;
    #pragma unroll
    for (int i = 0; i < 3; ++i) {
        int c = threadIdx.x + i * 256;
        v[i] = (c < Nn_) ? src[c] : -1e30f;
        mx = fmaxf(mx, v[i]);
    }
    mx = bmax(mx, sm);
    float s = 0.f;
    #pragma unroll
    for (int i = 0; i < 3; ++i) {
        int c = threadIdx.x + i * 256;
        v[i] = (c < Nn_) ? expf(v[i] - mx) : 0.f;
        s += v[i];
    }
    s = bsum(s, sm + 4);
    float inv = 1.f / s;
    #pragma unroll
    for (int i = 0; i < 3; ++i) {
        int c = threadIdx.x + i * 256;
        float p = v[i] * inv;
        if (c < Np) dst[c] = (c < Nn_) ? f2b(p) : (ushort_t)0;
        if (r == 0 && c >= 1 && c < Nn_) tok[(long long)b_l * 576 + (c - 1)] = p;
    }
}

// ---------------- bf16 MFMA GEMM: C[m,n] = alpha*sum_k A[m,k]*B[n,k] (+epilogue) ----------------
// A: M x K rows (lda), row-clamped. B: Nv x K rows (ldb), row-clamped.
// z-dim: batch index (strides sAb/sBb/sOb).
// K must be a multiple of 64 (all call sites: 640/768/3072).
// LDS uses XOR-swizzled 16B quarters: slot q' holds global quarter q'^(row&3),
// applied on the global-source side (global_load_lds lane->LDS map is fixed).
// K-loop is the T3-minimum 2-phase schedule: double-buffered LDS, stage of
// tile t+1 issued BEFORE compute of tile t, single __syncthreads per K-step
// (its implicit vmcnt(0) waits on loads that had a full MFMA phase in flight).
#define EPS_STORE  0
#define EPS_X2     1
#define EPS_GELU   2
#define EPS_ADD    3
#define EPS_QKV    4

#define MM_STAGE(AS, BS, k0) do {            \
    gl16(Ag0 + (k0), &AS[e0]);               \
    gl16(Ag1 + (k0), &AS[e1]);               \
    gl16(Bg0 + (k0), &BS[e0]);               \
    gl16(Bg1 + (k0), &BS[e1]);               \
} while (0)

#define MM_COMPUTE(AS, BS) do {                                             \
    short8 af[4], bfr[4];                                                   \
    _Pragma("unroll")                                                       \
    for (int i = 0; i < 4; ++i) {                                           \
        int r = wr + i * 16 + fr;                                           \
        af[i] = *(const short8*)&AS[r * 32 + ((kq ^ (r & 3)) << 3)];        \
    }                                                                       \
    _Pragma("unroll")                                                       \
    for (int j = 0; j < 4; ++j) {                                           \
        int r = wc + j * 16 + fr;                                           \
        bfr[j] = *(const short8*)&BS[r * 32 + ((kq ^ (r & 3)) << 3)];       \
    }                                                                       \
    _Pragma("unroll")                                                       \
    for (int i = 0; i < 4; ++i)                                             \
        _Pragma("unroll")                                                   \
        for (int j = 0; j < 4; ++j)                                         \
            acc[i][j] = __builtin_amdgcn_mfma_f32_16x16x32_bf16(            \
                af[i], bfr[j], acc[i][j], 0, 0, 0);                         \
} while (0)

template<int EPI, typename OutT>
__global__ __launch_bounds__(256)
void mm_bf16(const ushort_t* __restrict__ A, long long sAb, int lda, int M,
             const ushort_t* __restrict__ B, long long sBb, int ldb, int Nv,
             const float* __restrict__ bias,
             OutT* __restrict__ O, long long sOb, int ldo,
             int K, float alpha,
             ushort_t* __restrict__ qQ, ushort_t* __restrict__ qK, ushort_t* __restrict__ qV)
{
    __shared__ __align__(16) ushort_t As0[128 * 32];
    __shared__ __align__(16) ushort_t As1[128 * 32];
    __shared__ __align__(16) ushort_t Bs0[128 * 32];
    __shared__ __align__(16) ushort_t Bs1[128 * 32];
    const int z = blockIdx.z;
    A += (long long)z * sAb; B += (long long)z * sBb;
    if (O) O += (long long)z * sOb;
    const int n0 = blockIdx.x * 128;
    const int m0 = blockIdx.y * 128;
    const int tid = threadIdx.x;
    const int lane = tid & 63;
    const int wv = tid >> 6;
    const int wr = (wv >> 1) << 6;       // wave row offset in tile
    const int wc = (wv & 1) << 6;        // wave col offset in tile
    const int fr = lane & 15;
    const int kq = lane >> 4;            // k-quarter 0..3

    // staging: LDS chunk element e (ushorts) -> row = e>>5, lds quarter q' = (e&31)>>3,
    // source global quarter q = q' ^ (row&3).
    const int e0 = tid * 8, e1 = 2048 + tid * 8;
    const int ra0 = e0 >> 5, qa0 = (((e0 & 31) >> 3) ^ (ra0 & 3)) << 3;
    const int ra1 = e1 >> 5, qa1 = (((e1 & 31) >> 3) ^ (ra1 & 3)) << 3;
    const ushort_t* Ag0 = A + (long long)min(m0 + ra0, M - 1) * lda + qa0;
    const ushort_t* Ag1 = A + (long long)min(m0 + ra1, M - 1) * lda + qa1;
    const ushort_t* Bg0 = B + (long long)min(n0 + ra0, Nv - 1) * ldb + qa0;
    const ushort_t* Bg1 = B + (long long)min(n0 + ra1, Nv - 1) * ldb + qa1;

    f32x4 acc[4][4] = {};

    const int nt = K >> 5;               // even (K % 64 == 0)

    // prologue: stage tile 0 into buf0; barrier publishes it
    MM_STAGE(As0, Bs0, 0);
    __syncthreads();

    for (int t = 0; t < nt; t += 2) {
        // even step: prefetch tile t+1 into buf1, compute tile t from buf0
        MM_STAGE(As1, Bs1, (t + 1) << 5);
        MM_COMPUTE(As0, Bs0);
        __syncthreads();                 // vmcnt(0): buf1 ready; WAR: buf0 free
        // odd step: prefetch tile t+2 into buf0, compute tile t+1 from buf1
        if (t + 2 < nt) MM_STAGE(As0, Bs0, (t + 2) << 5);
        MM_COMPUTE(As1, Bs1);
        __syncthreads();
    }

    // epilogue: C row m = m0+wr+i*16+(lane>>4)*4+r ; col n = n0+wc+j*16+(lane&15)
    #pragma unroll
    for (int i = 0; i < 4; ++i) {
        int mb = m0 + wr + i * 16 + (lane >> 4) * 4;
        #pragma unroll
        for (int j = 0; j < 4; ++j) {
            int n = n0 + wc + j * 16 + fr;
            if (n >= Nv) continue;
            f32x4 v4 = acc[i][j];
            #pragma unroll
            for (int r = 0; r < 4; ++r) {
                int m = mb + r;
                if (m >= M) continue;
                float v = v4[r] * alpha;
                if constexpr (EPI == EPS_QKV) {
                    int b_l = m / Nn_, rr = m - b_l * Nn_;
                    if (n < Cc)            qQ[(long long)m * Cc + n] = f2b(v);
                    else if (n < 2 * Cc)   qK[(long long)m * Cc + (n - Cc)] = f2b(v);
                    else                   qV[((long long)b_l * Cc + (n - 2 * Cc)) * Np + rr] = f2b(v);
                } else if constexpr (EPI == EPS_ADD) {
                    if (bias) v += bias[n];
                    long long oi = (long long)m * ldo + n;
                    O[oi] += v;          // single owner per output: plain RMW
                } else {
                    if (bias) v += bias[n];
                    if constexpr (EPI == EPS_X2) v *= 2.f;
                    if constexpr (EPI == EPS_GELU) v = 0.5f * v * (1.f + erff(v * 0.70710678118654752f));
                    long long oi = (long long)m * ldo + n;
                    if constexpr (sizeof(OutT) == 2) O[oi] = (OutT)f2b(v);
                    else                             O[oi] = (OutT)v;
                }
            }
        }
    }
}

// ---------------- launcher ----------------
extern "C" void kernel_launch(void* const* d_in, const int* in_sizes, int n_in,
                              void* d_out, int out_size, void* d_ws, size_t ws_size,
                              hipStream_t stream) {
    const float* x      = (const float*)d_in[0];
    const float* n1w    = (const float*)d_in[1];
    const float* n1b    = (const float*)d_in[2];
    const float* qkv_w  = (const float*)d_in[3];
    const float* proj_w = (const float*)d_in[4];
    const float* proj_b = (const float*)d_in[5];
    const float* n2w    = (const float*)d_in[6];
    const float* n2b    = (const float*)d_in[7];
    const float* fc1w   = (const float*)d_in[8];
    const float* fc1b   = (const float*)d_in[9];
    const float* fc2w   = (const float*)d_in[10];
    const float* fc2b   = (const float*)d_in[11];
    float* out = (float*)d_out;
    float* x2  = out;
    float* tok = out + OUT_X;

    // ---- persistent bf16 weights at ws start ----
    char* ws = (char*)d_ws;
    const long long nWq = (long long)3 * Cc * Cc;
    const long long nWp = (long long)Cc * Cc;
    const long long nW1 = (long long)Hh * Cc;
    const long long nW2 = (long long)Cc * Hh;
    ushort_t* wq = (ushort_t*)ws;
    ushort_t* wp = wq + nWq;
    ushort_t* w1 = wp + nWp;
    ushort_t* w2 = w1 + nW1;
    const long long WBYTES = 2 * (nWq + nWp + nW1 + nW2); // 14,155,776
    char* dyn = ws + WBYTES;
    long long avail = (long long)ws_size - WBYTES;

    // ---- adaptive sizes (prefer no chunking: G=32, CH=full) ----
    const long long perG = 3LL * Nn_ * Cc * 2 + (long long)Cc * Np * 2
                         + (long long)Nn_ * Np * 4 + (long long)Nn_ * Np * 2;
    int G = 1;
    { const int o[6] = {32, 16, 8, 4, 2, 1};
      for (int i = 0; i < 6; ++i) if ((long long)o[i] * perG <= avail) { G = o[i]; break; } }
    int CH = Nn_;
    { const int o[6] = {32, 16, 8, 4, 2, 1};
      for (int i = 0; i < 6; ++i) if ((long long)o[i] * Nn_ * (Cc + Hh) * 2 <= avail) { CH = o[i] * Nn_; break; } }

    // phase A layout: hbf/Yt | Q | Kb | Vt | Sf | Sb
    ushort_t* hbf = (ushort_t*)dyn;
    ushort_t* Q   = hbf + (long long)G * Nn_ * Cc;
    ushort_t* Kb  = Q   + (long long)G * Nn_ * Cc;
    ushort_t* Vt  = Kb  + (long long)G * Nn_ * Cc;
    float*    Sf  = (float*)(Vt + (long long)G * Cc * Np);
    ushort_t* Sb  = (ushort_t*)(Sf + (long long)G * Nn_ * Np);
    ushort_t* Yt  = hbf;
    // phase B layout: g | t
    ushort_t* g = (ushort_t*)dyn;
    ushort_t* t = g + (long long)CH * Cc;

    // ---- weight conversion (every call; ws is re-poisoned) ----
    cvt_kernel<<<(int)((nWq + 255) / 256), 256, 0, stream>>>(qkv_w, wq, (int)nWq);
    cvt_kernel<<<(int)((nWp + 255) / 256), 256, 0, stream>>>(proj_w, wp, (int)nWp);
    cvt_kernel<<<(int)((nW1 + 255) / 256), 256, 0, stream>>>(fc1w, w1, (int)nW1);
    cvt_kernel<<<(int)((nW2 + 255) / 256), 256, 0, stream>>>(fc2w, w2, (int)nW2);

    // ================= phase A: attention per group of G batches =================
    for (int b0 = 0; b0 < Bz; b0 += G) {
        const int MR = G * Nn_;
        const int myM = (MR + 127) / 128;

        ln_bf16<<<MR, 256, 0, stream>>>(x + (long long)b0 * Nn_ * Cc, n1w, n1b, hbf);

        // qkv: (MR x 2304 x 768), scatter to Q | Kb | Vt
        mm_bf16<EPS_QKV, float><<<dim3(18, myM, 1), 256, 0, stream>>>(
            hbf, 0, Cc, MR, wq, 0, Cc, 3 * Cc, nullptr,
            (float*)nullptr, 0, 0, Cc, 1.f, Q, Kb, Vt);

        // Sf = scale * Q @ K^T per batch (577x577 valid, ld 640)
        mm_bf16<EPS_STORE, float><<<dim3(5, 5, G), 256, 0, stream>>>(
            Q, (long long)Nn_ * Cc, Cc, Nn_, Kb, (long long)Nn_ * Cc, Cc, Nn_, nullptr,
            Sf, (long long)Nn_ * Np, Np, Cc, SCALE, nullptr, nullptr, nullptr);

        softmax_bf16<<<MR, 256, 0, stream>>>(Sf, Sb, tok + (long long)b0 * 576);

        // Yt[c, n] = sum_m Vt[c, m] * Sb[n, m]  (M=768, N=577 valid, K=640)
        mm_bf16<EPS_STORE, ushort_t><<<dim3(5, 6, G), 256, 0, stream>>>(
            Vt, (long long)Cc * Np, Np, Cc, Sb, (long long)Nn_ * Np, Np, Nn_, nullptr,
            Yt, (long long)Cc * Nn_, Nn_, Np, 1.f, nullptr, nullptr, nullptr);

        // x2 = 2*(Yt_flat @ proj_w^T + proj_b) -> d_out rows of group (fp32)
        mm_bf16<EPS_X2, float><<<dim3(6, myM, 1), 256, 0, stream>>>(
            Yt, 0, Cc, MR, wp, 0, Cc, Cc, proj_b,
            x2 + (long long)b0 * Nn_ * Cc, 0, Cc, Cc, 1.f, nullptr, nullptr, nullptr);
    }

    // ================= phase B: MLP per chunk of CH rows =================
    for (int c0 = 0; c0 < Mrows; c0 += CH) {
        const int cn = (Mrows - c0 < CH) ? (Mrows - c0) : CH;
        const int myC = (cn + 127) / 128;

        ln_bf16<<<cn, 256, 0, stream>>>(x2 + (long long)c0 * Cc, n2w, n2b, g);

        // t = gelu(g @ fc1^T + b1)  (cn x 3072 x 768), bf16
        mm_bf16<EPS_GELU, ushort_t><<<dim3(24, myC, 1), 256, 0, stream>>>(
            g, 0, Cc, cn, w1, 0, Cc, Hh, fc1b,
            t, 0, Hh, Cc, 1.f, nullptr, nullptr, nullptr);

        // x2 += t @ fc2^T + b2  (cn x 768 x 3072), single-K, plain += epilogue
        mm_bf16<EPS_ADD, float><<<dim3(6, myC, 1), 256, 0, stream>>>(
            t, 0, Hh, cn, w2, 0, Hh, Cc, fc2b,
            x2 + (long long)c0 * Cc, 0, Cc, Hh, 1.f, nullptr, nullptr, nullptr);
    }
}

// Round 3
// 872.054 us; speedup vs baseline: 1.0518x; 1.0205x over previous
//
#include <hip/hip_runtime.h>
#include <hip/hip_bf16.h>

// ---------------- problem constants ----------------
#define Bz   32
#define Nn_  577
#define Np   640                    // 577 padded to 5*128
#define Cc   768
#define Hh   3072
#define Mrows (Bz * Nn_)            // 18464
#define OUT_X (Mrows * Cc)          // 14,180,352 floats
#define SCALE 0.03608439182435161f  // 768^-0.5

typedef unsigned short ushort_t;
typedef short short8 __attribute__((ext_vector_type(8)));
typedef float f32x4 __attribute__((ext_vector_type(4)));

__device__ __forceinline__ ushort_t f2b(float f) {
    __hip_bfloat16 h = __float2bfloat16(f);
    return *reinterpret_cast<ushort_t*>(&h);
}

// ---------------- async global->LDS (16B per lane) ----------------
__device__ __forceinline__ void gl16(const ushort_t* g, ushort_t* l) {
    __builtin_amdgcn_global_load_lds(
        (const __attribute__((address_space(1))) void*)g,
        (__attribute__((address_space(3))) void*)l, 16, 0, 0);
}

// ---------------- block reduction helpers (256-thread blocks) ----------------
__device__ __forceinline__ float bsum(float v, float* sm) {
    #pragma unroll
    for (int o = 32; o > 0; o >>= 1) v += __shfl_down(v, o, 64);
    int lane = threadIdx.x & 63, wid = threadIdx.x >> 6;
    if (lane == 0) sm[wid] = v;
    __syncthreads();
    float r = sm[0] + sm[1] + sm[2] + sm[3];
    __syncthreads();
    return r;
}
__device__ __forceinline__ float bmax(float v, float* sm) {
    #pragma unroll
    for (int o = 32; o > 0; o >>= 1) v = fmaxf(v, __shfl_down(v, o, 64));
    int lane = threadIdx.x & 63, wid = threadIdx.x >> 6;
    if (lane == 0) sm[wid] = v;
    __syncthreads();
    float r = fmaxf(fmaxf(sm[0], sm[1]), fmaxf(sm[2], sm[3]));
    __syncthreads();
    return r;
}

// ---------------- fp32 -> bf16 convert ----------------
__global__ void cvt_kernel(const float* __restrict__ in, ushort_t* __restrict__ out, int n) {
    int i = blockIdx.x * 256 + threadIdx.x;
    if (i < n) out[i] = f2b(in[i]);
}

// ---------------- LayerNorm: fp32 in, bf16 out ----------------
__global__ void ln_bf16(const float* __restrict__ x, const float* __restrict__ w,
                        const float* __restrict__ b, ushort_t* __restrict__ out) {
    __shared__ float sm[8];
    long long row = blockIdx.x;
    const float* xr = x + row * Cc;
    float v[3]; float s = 0.f;
    #pragma unroll
    for (int i = 0; i < 3; ++i) { v[i] = xr[threadIdx.x + i * 256]; s += v[i]; }
    float mu = bsum(s, sm) * (1.f / (float)Cc);
    float sq = 0.f;
    #pragma unroll
    for (int i = 0; i < 3; ++i) { float d = v[i] - mu; sq += d * d; }
    float var = bsum(sq, sm + 4) * (1.f / (float)Cc);
    float inv = rsqrtf(var + 1e-5f);
    ushort_t* orow = out + row * Cc;
    #pragma unroll
    for (int i = 0; i < 3; ++i) {
        int c = threadIdx.x + i * 256;
        orow[c] = f2b((v[i] - mu) * inv * w[c] + b[c]);
    }
}

// ---------------- softmax: fp32 Sf (ld 640, 577 valid) -> bf16 Sb (zero-padded) + tok ----------------
__global__ void softmax_bf16(const float* __restrict__ Sf, ushort_t* __restrict__ Sb,
                             float* __restrict__ tok) {
    __shared__ float sm[8];
    long long row = blockIdx.x;
    int b_l = (int)(row / Nn_), r = (int)(row - (long long)b_l * Nn_);
    const float* src = Sf + row * Np;
    ushort_t* dst = Sb + row * Np;
    float v[3]; float mx = -1e30f;
    #pragma unroll
    for (int i = 0; i < 3; ++i) {
        int c = threadIdx.x + i * 256;
        v[i] = (c < Nn_) ? src[c] : -1e30f;
        mx = fmaxf(mx, v[i]);
    }
    mx = bmax(mx, sm);
    float s = 0.f;
    #pragma unroll
    for (int i = 0; i < 3; ++i) {
        int c = threadIdx.x + i * 256;
        v[i] = (c < Nn_) ? expf(v[i] - mx) : 0.f;
        s += v[i];
    }
    s = bsum(s, sm + 4);
    float inv = 1.f / s;
    #pragma unroll
    for (int i = 0; i < 3; ++i) {
        int c = threadIdx.x + i * 256;
        float p = v[i] * inv;
        if (c < Np) dst[c] = (c < Nn_) ? f2b(p) : (ushort_t)0;
        if (r == 0 && c >= 1 && c < Nn_) tok[(long long)b_l * 576 + (c - 1)] = p;
    }
}

// ---------------- epilogue selectors ----------------
#define EPS_STORE  0
#define EPS_X2     1
#define EPS_GELU   2
#define EPS_ADD    3
#define EPS_QKV    4

// =====================================================================
// 128x128 / BK=32 / 4-wave kernel (2-phase dbuf) — kept for batched QK^T / PV
// =====================================================================
#define MM_STAGE(AS, BS, k0) do {            \
    gl16(Ag0 + (k0), &AS[e0]);               \
    gl16(Ag1 + (k0), &AS[e1]);               \
    gl16(Bg0 + (k0), &BS[e0]);               \
    gl16(Bg1 + (k0), &BS[e1]);               \
} while (0)

#define MM_COMPUTE(AS, BS) do {                                             \
    short8 af[4], bfr[4];                                                   \
    _Pragma("unroll")                                                       \
    for (int i = 0; i < 4; ++i) {                                           \
        int r = wr + i * 16 + fr;                                           \
        af[i] = *(const short8*)&AS[r * 32 + ((kq ^ (r & 3)) << 3)];        \
    }                                                                       \
    _Pragma("unroll")                                                       \
    for (int j = 0; j < 4; ++j) {                                           \
        int r = wc + j * 16 + fr;                                           \
        bfr[j] = *(const short8*)&BS[r * 32 + ((kq ^ (r & 3)) << 3)];       \
    }                                                                       \
    _Pragma("unroll")                                                       \
    for (int i = 0; i < 4; ++i)                                             \
        _Pragma("unroll")                                                   \
        for (int j = 0; j < 4; ++j)                                         \
            acc[i][j] = __builtin_amdgcn_mfma_f32_16x16x32_bf16(            \
                af[i], bfr[j], acc[i][j], 0, 0, 0);                         \
} while (0)

template<int EPI, typename OutT>
__global__ __launch_bounds__(256)
void mm_bf16(const ushort_t* __restrict__ A, long long sAb, int lda, int M,
             const ushort_t* __restrict__ B, long long sBb, int ldb, int Nv,
             const float* __restrict__ bias,
             OutT* __restrict__ O, long long sOb, int ldo,
             int K, float alpha,
             ushort_t* __restrict__ qQ, ushort_t* __restrict__ qK, ushort_t* __restrict__ qV)
{
    __shared__ __align__(16) ushort_t As0[128 * 32];
    __shared__ __align__(16) ushort_t As1[128 * 32];
    __shared__ __align__(16) ushort_t Bs0[128 * 32];
    __shared__ __align__(16) ushort_t Bs1[128 * 32];
    const int z = blockIdx.z;
    A += (long long)z * sAb; B += (long long)z * sBb;
    if (O) O += (long long)z * sOb;
    const int n0 = blockIdx.x * 128;
    const int m0 = blockIdx.y * 128;
    const int tid = threadIdx.x;
    const int lane = tid & 63;
    const int wv = tid >> 6;
    const int wr = (wv >> 1) << 6;       // wave row offset in tile
    const int wc = (wv & 1) << 6;        // wave col offset in tile
    const int fr = lane & 15;
    const int kq = lane >> 4;            // k-quarter 0..3

    const int e0 = tid * 8, e1 = 2048 + tid * 8;
    const int ra0 = e0 >> 5, qa0 = (((e0 & 31) >> 3) ^ (ra0 & 3)) << 3;
    const int ra1 = e1 >> 5, qa1 = (((e1 & 31) >> 3) ^ (ra1 & 3)) << 3;
    const ushort_t* Ag0 = A + (long long)min(m0 + ra0, M - 1) * lda + qa0;
    const ushort_t* Ag1 = A + (long long)min(m0 + ra1, M - 1) * lda + qa1;
    const ushort_t* Bg0 = B + (long long)min(n0 + ra0, Nv - 1) * ldb + qa0;
    const ushort_t* Bg1 = B + (long long)min(n0 + ra1, Nv - 1) * ldb + qa1;

    f32x4 acc[4][4] = {};

    const int nt = K >> 5;               // even (K % 64 == 0)

    MM_STAGE(As0, Bs0, 0);
    __syncthreads();

    for (int t = 0; t < nt; t += 2) {
        MM_STAGE(As1, Bs1, (t + 1) << 5);
        MM_COMPUTE(As0, Bs0);
        __syncthreads();
        if (t + 2 < nt) MM_STAGE(As0, Bs0, (t + 2) << 5);
        MM_COMPUTE(As1, Bs1);
        __syncthreads();
    }

    #pragma unroll
    for (int i = 0; i < 4; ++i) {
        int mb = m0 + wr + i * 16 + (lane >> 4) * 4;
        #pragma unroll
        for (int j = 0; j < 4; ++j) {
            int n = n0 + wc + j * 16 + fr;
            if (n >= Nv) continue;
            f32x4 v4 = acc[i][j];
            #pragma unroll
            for (int r = 0; r < 4; ++r) {
                int m = mb + r;
                if (m >= M) continue;
                float v = v4[r] * alpha;
                if constexpr (EPI == EPS_QKV) {
                    int b_l = m / Nn_, rr = m - b_l * Nn_;
                    if (n < Cc)            qQ[(long long)m * Cc + n] = f2b(v);
                    else if (n < 2 * Cc)   qK[(long long)m * Cc + (n - Cc)] = f2b(v);
                    else                   qV[((long long)b_l * Cc + (n - 2 * Cc)) * Np + rr] = f2b(v);
                } else if constexpr (EPI == EPS_ADD) {
                    if (bias) v += bias[n];
                    long long oi = (long long)m * ldo + n;
                    O[oi] += v;
                } else {
                    if (bias) v += bias[n];
                    if constexpr (EPI == EPS_X2) v *= 2.f;
                    if constexpr (EPI == EPS_GELU) v = 0.5f * v * (1.f + erff(v * 0.70710678118654752f));
                    long long oi = (long long)m * ldo + n;
                    if constexpr (sizeof(OutT) == 2) O[oi] = (OutT)f2b(v);
                    else                             O[oi] = (OutT)v;
                }
            }
        }
    }
}

// =====================================================================
// 256x256 / BK=64 / 8-wave deep-pipelined GEMM (T1+T2+T3/T4+T5 combo)
// LDS 128KB: 2 dbuf x (A 32KB + B 32KB). Row = 64 bf16 = 128B = 8 x 16B
// chunks; physical chunk p holds logical chunk p ^ (row&7)  (T2 swizzle,
// involution, applied on the global-source side since global_load_lds
// writes linearly). K-loop: stage tile t+1 -> s_waitcnt vmcnt(8) (tile t
// landed, t+1 still in flight; never vmcnt(0) mid-loop) -> s_barrier ->
// 4 phases x {4 ds_read_b128 A; setprio(1); 16 MFMA; setprio(0)} ->
// s_barrier (WAR before next stage overwrites this buffer).
// =====================================================================
#define STAGE256(LA, LB, kt) do {                                   \
    _Pragma("unroll")                                               \
    for (int j = 0; j < 4; ++j) gl16(Ag[j] + (kt) * 64, &LA[j * 4096 + sdst]); \
    _Pragma("unroll")                                               \
    for (int j = 0; j < 4; ++j) gl16(Bg[j] + (kt) * 64, &LB[j * 4096 + sdst]); \
} while (0)

#define COMPUTE256(LA, LB) do {                                                   \
    short8 bfv[4][2];                                                             \
    _Pragma("unroll")                                                             \
    for (int nf = 0; nf < 4; ++nf) {                                              \
        int rb = (wn64 + nf * 16 + fr) * 64;                                      \
        bfv[nf][0] = *(const short8*)&LB[rb + ck0];                               \
        bfv[nf][1] = *(const short8*)&LB[rb + ck1];                               \
    }                                                                             \
    _Pragma("unroll")                                                             \
    for (int mh = 0; mh < 4; ++mh) {                                              \
        int ra0 = (wm128 + mh * 32 + fr) * 64;                                    \
        int ra1 = (wm128 + mh * 32 + 16 + fr) * 64;                               \
        short8 a00 = *(const short8*)&LA[ra0 + ck0];                              \
        short8 a01 = *(const short8*)&LA[ra0 + ck1];                              \
        short8 a10 = *(const short8*)&LA[ra1 + ck0];                              \
        short8 a11 = *(const short8*)&LA[ra1 + ck1];                              \
        __builtin_amdgcn_s_setprio(1);                                            \
        _Pragma("unroll")                                                         \
        for (int nf = 0; nf < 4; ++nf) {                                          \
            acc[mh*2][nf]   = __builtin_amdgcn_mfma_f32_16x16x32_bf16(a00, bfv[nf][0], acc[mh*2][nf],   0,0,0); \
            acc[mh*2][nf]   = __builtin_amdgcn_mfma_f32_16x16x32_bf16(a01, bfv[nf][1], acc[mh*2][nf],   0,0,0); \
            acc[mh*2+1][nf] = __builtin_amdgcn_mfma_f32_16x16x32_bf16(a10, bfv[nf][0], acc[mh*2+1][nf], 0,0,0); \
            acc[mh*2+1][nf] = __builtin_amdgcn_mfma_f32_16x16x32_bf16(a11, bfv[nf][1], acc[mh*2+1][nf], 0,0,0); \
        }                                                                         \
        __builtin_amdgcn_s_setprio(0);                                            \
    }                                                                             \
} while (0)

#define TILE_STEP256(RA, RB, WA, WB, kt) do {                       \
    if ((kt) + 1 < nt) {                                            \
        STAGE256(WA, WB, (kt) + 1);                                 \
        asm volatile("s_waitcnt vmcnt(8)" ::: "memory");            \
    } else {                                                        \
        asm volatile("s_waitcnt vmcnt(0)" ::: "memory");            \
    }                                                               \
    __builtin_amdgcn_s_barrier();                                   \
    __builtin_amdgcn_sched_barrier(0);                              \
    COMPUTE256(RA, RB);                                             \
    __builtin_amdgcn_s_barrier();                                   \
    __builtin_amdgcn_sched_barrier(0);                              \
} while (0)

template<int EPI, typename OutT>
__global__ __launch_bounds__(512, 2)
void mm256(const ushort_t* __restrict__ A, int lda, int M,
           const ushort_t* __restrict__ B, int ldb, int Nv,
           const float* __restrict__ bias,
           OutT* __restrict__ O, int ldo,
           int K, float alpha,
           ushort_t* __restrict__ qQ, ushort_t* __restrict__ qK, ushort_t* __restrict__ qV)
{
    __shared__ __align__(16) ushort_t As0[256 * 64];
    __shared__ __align__(16) ushort_t Bs0[256 * 64];
    __shared__ __align__(16) ushort_t As1[256 * 64];
    __shared__ __align__(16) ushort_t Bs1[256 * 64];

    // T1: bijective XCD-aware remap (m204 formula) — neighbors sharing the
    // A row-panel land on the same XCD's L2.
    const int nwg = gridDim.x * gridDim.y;
    const int flat = blockIdx.y * gridDim.x + blockIdx.x;
    const int qq = nwg >> 3, rr8 = nwg & 7;
    const int xcd = flat & 7, idx = flat >> 3;
    const int wg = (xcd < rr8 ? xcd * (qq + 1) : rr8 * (qq + 1) + (xcd - rr8) * qq) + idx;
    const int bx = wg % gridDim.x, by = wg / gridDim.x;

    const int n0 = bx * 256, m0 = by * 256;
    const int tid = (int)threadIdx.x;
    const int lane = tid & 63;
    const int wv = tid >> 6;            // 0..7
    const int wm128 = (wv >> 2) * 128;  // wave row offset (2 M-halves)
    const int wn64  = (wv & 3) * 64;    // wave col offset (4 N-quarters)
    const int fr = lane & 15;
    const int kq = lane >> 4;           // k-chunk-in-32 0..3
    const int f7 = fr & 7;
    const int ck0 = (kq ^ f7) * 8;           // ushort offset, k-slice 0 chunk
    const int ck1 = ((4 + kq) ^ f7) * 8;     // k-slice 1 chunk

    // staging: thread tid, round j covers row j*64 + (tid>>3), physical chunk tid&7;
    // source logical chunk = (tid&7) ^ (row&7)  (row&7 == (tid>>3)&7 for all rounds)
    const int srow = tid >> 3;
    const int schunk = (tid & 7) ^ (srow & 7);
    const int sdst = tid * 8;           // ushort offset within an 8KB round
    const ushort_t* Ag[4];
    const ushort_t* Bg[4];
    #pragma unroll
    for (int j = 0; j < 4; ++j) {
        Ag[j] = A + (long long)min(m0 + j * 64 + srow, M - 1) * lda + schunk * 8;
        Bg[j] = B + (long long)min(n0 + j * 64 + srow, Nv - 1) * ldb + schunk * 8;
    }

    f32x4 acc[8][4] = {};
    const int nt = K >> 6;              // even at all call sites (768/3072)

    STAGE256(As0, Bs0, 0);              // 8 loads in flight

    for (int t = 0; t < nt; t += 2) {
        TILE_STEP256(As0, Bs0, As1, Bs1, t);
        TILE_STEP256(As1, Bs1, As0, Bs0, t + 1);
    }

    // epilogue: m = m0 + wm128 + mf*16 + (lane>>4)*4 + r ; n = n0 + wn64 + nf*16 + fr
    #pragma unroll
    for (int mf = 0; mf < 8; ++mf) {
        int mb = m0 + wm128 + mf * 16 + (lane >> 4) * 4;
        #pragma unroll
        for (int nf = 0; nf < 4; ++nf) {
            int n = n0 + wn64 + nf * 16 + fr;
            if (n >= Nv) continue;
            f32x4 v4 = acc[mf][nf];
            #pragma unroll
            for (int r = 0; r < 4; ++r) {
                int m = mb + r;
                if (m >= M) continue;
                float v = v4[r] * alpha;
                if constexpr (EPI == EPS_QKV) {
                    int b_l = m / Nn_, rq = m - b_l * Nn_;
                    if (n < Cc)            qQ[(long long)m * Cc + n] = f2b(v);
                    else if (n < 2 * Cc)   qK[(long long)m * Cc + (n - Cc)] = f2b(v);
                    else                   qV[((long long)b_l * Cc + (n - 2 * Cc)) * Np + rq] = f2b(v);
                } else if constexpr (EPI == EPS_ADD) {
                    if (bias) v += bias[n];
                    long long oi = (long long)m * ldo + n;
                    O[oi] += v;          // single owner per output
                } else {
                    if (bias) v += bias[n];
                    if constexpr (EPI == EPS_X2) v *= 2.f;
                    if constexpr (EPI == EPS_GELU) v = 0.5f * v * (1.f + erff(v * 0.70710678118654752f));
                    long long oi = (long long)m * ldo + n;
                    if constexpr (sizeof(OutT) == 2) O[oi] = (OutT)f2b(v);
                    else                             O[oi] = (OutT)v;
                }
            }
        }
    }
}

// ---------------- launcher ----------------
extern "C" void kernel_launch(void* const* d_in, const int* in_sizes, int n_in,
                              void* d_out, int out_size, void* d_ws, size_t ws_size,
                              hipStream_t stream) {
    const float* x      = (const float*)d_in[0];
    const float* n1w    = (const float*)d_in[1];
    const float* n1b    = (const float*)d_in[2];
    const float* qkv_w  = (const float*)d_in[3];
    const float* proj_w = (const float*)d_in[4];
    const float* proj_b = (const float*)d_in[5];
    const float* n2w    = (const float*)d_in[6];
    const float* n2b    = (const float*)d_in[7];
    const float* fc1w   = (const float*)d_in[8];
    const float* fc1b   = (const float*)d_in[9];
    const float* fc2w   = (const float*)d_in[10];
    const float* fc2b   = (const float*)d_in[11];
    float* out = (float*)d_out;
    float* x2  = out;
    float* tok = out + OUT_X;

    // ---- persistent bf16 weights at ws start ----
    char* ws = (char*)d_ws;
    const long long nWq = (long long)3 * Cc * Cc;
    const long long nWp = (long long)Cc * Cc;
    const long long nW1 = (long long)Hh * Cc;
    const long long nW2 = (long long)Cc * Hh;
    ushort_t* wq = (ushort_t*)ws;
    ushort_t* wp = wq + nWq;
    ushort_t* w1 = wp + nWp;
    ushort_t* w2 = w1 + nW1;
    const long long WBYTES = 2 * (nWq + nWp + nW1 + nW2); // 14,155,776
    char* dyn = ws + WBYTES;
    long long avail = (long long)ws_size - WBYTES;

    // ---- adaptive sizes (prefer no chunking: G=32, CH=full) ----
    const long long perG = 3LL * Nn_ * Cc * 2 + (long long)Cc * Np * 2
                         + (long long)Nn_ * Np * 4 + (long long)Nn_ * Np * 2;
    int G = 1;
    { const int o[6] = {32, 16, 8, 4, 2, 1};
      for (int i = 0; i < 6; ++i) if ((long long)o[i] * perG <= avail) { G = o[i]; break; } }
    int CH = Nn_;
    { const int o[6] = {32, 16, 8, 4, 2, 1};
      for (int i = 0; i < 6; ++i) if ((long long)o[i] * Nn_ * (Cc + Hh) * 2 <= avail) { CH = o[i] * Nn_; break; } }

    // phase A layout: hbf/Yt | Q | Kb | Vt | Sf | Sb
    ushort_t* hbf = (ushort_t*)dyn;
    ushort_t* Q   = hbf + (long long)G * Nn_ * Cc;
    ushort_t* Kb  = Q   + (long long)G * Nn_ * Cc;
    ushort_t* Vt  = Kb  + (long long)G * Nn_ * Cc;
    float*    Sf  = (float*)(Vt + (long long)G * Cc * Np);
    ushort_t* Sb  = (ushort_t*)(Sf + (long long)G * Nn_ * Np);
    ushort_t* Yt  = hbf;
    // phase B layout: g | t
    ushort_t* g = (ushort_t*)dyn;
    ushort_t* t = g + (long long)CH * Cc;

    // ---- weight conversion (every call; ws is re-poisoned) ----
    cvt_kernel<<<(int)((nWq + 255) / 256), 256, 0, stream>>>(qkv_w, wq, (int)nWq);
    cvt_kernel<<<(int)((nWp + 255) / 256), 256, 0, stream>>>(proj_w, wp, (int)nWp);
    cvt_kernel<<<(int)((nW1 + 255) / 256), 256, 0, stream>>>(fc1w, w1, (int)nW1);
    cvt_kernel<<<(int)((nW2 + 255) / 256), 256, 0, stream>>>(fc2w, w2, (int)nW2);

    // ================= phase A: attention per group of G batches =================
    for (int b0 = 0; b0 < Bz; b0 += G) {
        const int MR = G * Nn_;
        const int myM256 = (MR + 255) / 256;

        ln_bf16<<<MR, 256, 0, stream>>>(x + (long long)b0 * Nn_ * Cc, n1w, n1b, hbf);

        // qkv: (MR x 2304 x 768), scatter to Q | Kb | Vt  (256-tile pipelined)
        mm256<EPS_QKV, float><<<dim3(9, myM256, 1), 512, 0, stream>>>(
            hbf, Cc, MR, wq, Cc, 3 * Cc, nullptr,
            (float*)nullptr, 0, Cc, 1.f, Q, Kb, Vt);

        // Sf = scale * Q @ K^T per batch (577x577 valid, ld 640) — 128-tile batched
        mm_bf16<EPS_STORE, float><<<dim3(5, 5, G), 256, 0, stream>>>(
            Q, (long long)Nn_ * Cc, Cc, Nn_, Kb, (long long)Nn_ * Cc, Cc, Nn_, nullptr,
            Sf, (long long)Nn_ * Np, Np, Cc, SCALE, nullptr, nullptr, nullptr);

        softmax_bf16<<<MR, 256, 0, stream>>>(Sf, Sb, tok + (long long)b0 * 576);

        // Yt[c, n] = sum_m Vt[c, m] * Sb[n, m]  (M=768, N=577 valid, K=640) — 128-tile batched
        mm_bf16<EPS_STORE, ushort_t><<<dim3(5, 6, G), 256, 0, stream>>>(
            Vt, (long long)Cc * Np, Np, Cc, Sb, (long long)Nn_ * Np, Np, Nn_, nullptr,
            Yt, (long long)Cc * Nn_, Nn_, Np, 1.f, nullptr, nullptr, nullptr);

        // x2 = 2*(Yt_flat @ proj_w^T + proj_b) -> d_out rows of group (fp32)
        mm256<EPS_X2, float><<<dim3(3, myM256, 1), 512, 0, stream>>>(
            Yt, Cc, MR, wp, Cc, Cc, proj_b,
            x2 + (long long)b0 * Nn_ * Cc, Cc, Cc, 1.f, nullptr, nullptr, nullptr);
    }

    // ================= phase B: MLP per chunk of CH rows =================
    for (int c0 = 0; c0 < Mrows; c0 += CH) {
        const int cn = (Mrows - c0 < CH) ? (Mrows - c0) : CH;
        const int myC256 = (cn + 255) / 256;

        ln_bf16<<<cn, 256, 0, stream>>>(x2 + (long long)c0 * Cc, n2w, n2b, g);

        // t = gelu(g @ fc1^T + b1)  (cn x 3072 x 768), bf16
        mm256<EPS_GELU, ushort_t><<<dim3(12, myC256, 1), 512, 0, stream>>>(
            g, Cc, cn, w1, Cc, Hh, fc1b,
            t, Hh, Cc, 1.f, nullptr, nullptr, nullptr);

        // x2 += t @ fc2^T + b2  (cn x 768 x 3072), plain += epilogue
        mm256<EPS_ADD, float><<<dim3(3, myC256, 1), 512, 0, stream>>>(
            t, Hh, cn, w2, Hh, Cc, fc2b,
            x2 + (long long)c0 * Cc, Cc, Hh, 1.f, nullptr, nullptr, nullptr);
    }
}

// Round 4
// 859.553 us; speedup vs baseline: 1.0671x; 1.0145x over previous
//
#include <hip/hip_runtime.h>
#include <hip/hip_bf16.h>

// ---------------- problem constants ----------------
#define Bz   32
#define Nn_  577
#define Np   640                    // 577 padded to 5*128
#define Cc   768
#define Hh   3072
#define Mrows (Bz * Nn_)            // 18464
#define OUT_X (Mrows * Cc)          // 14,180,352 floats
#define SCALE 0.03608439182435161f  // 768^-0.5

typedef unsigned short ushort_t;
typedef short short8 __attribute__((ext_vector_type(8)));
typedef float f32x4 __attribute__((ext_vector_type(4)));

__device__ __forceinline__ ushort_t f2b(float f) {
    __hip_bfloat16 h = __float2bfloat16(f);
    return *reinterpret_cast<ushort_t*>(&h);
}

// fast exact-GELU: erf via Abramowitz-Stegun 7.1.26 (|err| <= 1.5e-7)
__device__ __forceinline__ float gelu_f(float v) {
    float z  = v * 0.70710678118654752f;
    float az = fabsf(z);
    float t_ = __builtin_amdgcn_rcpf(1.f + 0.3275911f * az);
    float y  = t_ * (0.254829592f + t_ * (-0.284496736f + t_ * (1.421413741f +
               t_ * (-1.453152027f + t_ * 1.061405429f))));
    float e  = __expf(-az * az);
    float er = 1.f - y * e;
    er = (z < 0.f) ? -er : er;
    return 0.5f * v * (1.f + er);
}

// ---------------- async global->LDS (16B per lane) ----------------
__device__ __forceinline__ void gl16(const ushort_t* g, ushort_t* l) {
    __builtin_amdgcn_global_load_lds(
        (const __attribute__((address_space(1))) void*)g,
        (__attribute__((address_space(3))) void*)l, 16, 0, 0);
}

// ---------------- block reduction helpers (256-thread blocks) ----------------
__device__ __forceinline__ float bsum(float v, float* sm) {
    #pragma unroll
    for (int o = 32; o > 0; o >>= 1) v += __shfl_down(v, o, 64);
    int lane = threadIdx.x & 63, wid = threadIdx.x >> 6;
    if (lane == 0) sm[wid] = v;
    __syncthreads();
    float r = sm[0] + sm[1] + sm[2] + sm[3];
    __syncthreads();
    return r;
}
__device__ __forceinline__ float bmax(float v, float* sm) {
    #pragma unroll
    for (int o = 32; o > 0; o >>= 1) v = fmaxf(v, __shfl_down(v, o, 64));
    int lane = threadIdx.x & 63, wid = threadIdx.x >> 6;
    if (lane == 0) sm[wid] = v;
    __syncthreads();
    float r = fmaxf(fmaxf(sm[0], sm[1]), fmaxf(sm[2], sm[3]));
    __syncthreads();
    return r;
}

// ---------------- fp32 -> bf16 convert ----------------
__global__ void cvt_kernel(const float* __restrict__ in, ushort_t* __restrict__ out, int n) {
    int i = blockIdx.x * 256 + threadIdx.x;
    if (i < n) out[i] = f2b(in[i]);
}

// ---------------- LayerNorm: fp32 in, bf16 out ----------------
__global__ void ln_bf16(const float* __restrict__ x, const float* __restrict__ w,
                        const float* __restrict__ b, ushort_t* __restrict__ out) {
    __shared__ float sm[8];
    long long row = blockIdx.x;
    const float* xr = x + row * Cc;
    float v[3]; float s = 0.f;
    #pragma unroll
    for (int i = 0; i < 3; ++i) { v[i] = xr[threadIdx.x + i * 256]; s += v[i]; }
    float mu = bsum(s, sm) * (1.f / (float)Cc);
    float sq = 0.f;
    #pragma unroll
    for (int i = 0; i < 3; ++i) { float d = v[i] - mu; sq += d * d; }
    float var = bsum(sq, sm + 4) * (1.f / (float)Cc);
    float inv = rsqrtf(var + 1e-5f);
    ushort_t* orow = out + row * Cc;
    #pragma unroll
    for (int i = 0; i < 3; ++i) {
        int c = threadIdx.x + i * 256;
        orow[c] = f2b((v[i] - mu) * inv * w[c] + b[c]);
    }
}

// ---------------- softmax: fp32 Sf (ld 640, 577 valid) -> bf16 Sb (zero-padded) + tok ----------------
__global__ void softmax_bf16(const float* __restrict__ Sf, ushort_t* __restrict__ Sb,
                             float* __restrict__ tok) {
    __shared__ float sm[8];
    long long row = blockIdx.x;
    int b_l = (int)(row / Nn_), r = (int)(row - (long long)b_l * Nn_);
    const float* src = Sf + row * Np;
    ushort_t* dst = Sb + row * Np;
    float v[3]; float mx = -1e30f;
    #pragma unroll
    for (int i = 0; i < 3; ++i) {
        int c = threadIdx.x + i * 256;
        v[i] = (c < Nn_) ? src[c] : -1e30f;
        mx = fmaxf(mx, v[i]);
    }
    mx = bmax(mx, sm);
    float s = 0.f;
    #pragma unroll
    for (int i = 0; i < 3; ++i) {
        int c = threadIdx.x + i * 256;
        v[i] = (c < Nn_) ? expf(v[i] - mx) : 0.f;
        s += v[i];
    }
    s = bsum(s, sm + 4);
    float inv = 1.f / s;
    #pragma unroll
    for (int i = 0; i < 3; ++i) {
        int c = threadIdx.x + i * 256;
        float p = v[i] * inv;
        if (c < Np) dst[c] = (c < Nn_) ? f2b(p) : (ushort_t)0;
        if (r == 0 && c >= 1 && c < Nn_) tok[(long long)b_l * 576 + (c - 1)] = p;
    }
}

// ---------------- epilogue selectors ----------------
#define EPS_STORE  0
#define EPS_X2     1
#define EPS_GELU   2
#define EPS_ADD    3
#define EPS_QKV    4

// =====================================================================
// 128x128 / BK=32 / 4-wave kernel (2-phase dbuf) — kept for batched QK^T / PV
// =====================================================================
#define MM_STAGE(AS, BS, k0) do {            \
    gl16(Ag0 + (k0), &AS[e0]);               \
    gl16(Ag1 + (k0), &AS[e1]);               \
    gl16(Bg0 + (k0), &BS[e0]);               \
    gl16(Bg1 + (k0), &BS[e1]);               \
} while (0)

#define MM_COMPUTE(AS, BS) do {                                             \
    short8 af[4], bfr[4];                                                   \
    _Pragma("unroll")                                                       \
    for (int i = 0; i < 4; ++i) {                                           \
        int r = wr + i * 16 + fr;                                           \
        af[i] = *(const short8*)&AS[r * 32 + ((kq ^ (r & 3)) << 3)];        \
    }                                                                       \
    _Pragma("unroll")                                                       \
    for (int j = 0; j < 4; ++j) {                                           \
        int r = wc + j * 16 + fr;                                           \
        bfr[j] = *(const short8*)&BS[r * 32 + ((kq ^ (r & 3)) << 3)];       \
    }                                                                       \
    _Pragma("unroll")                                                       \
    for (int i = 0; i < 4; ++i)                                             \
        _Pragma("unroll")                                                   \
        for (int j = 0; j < 4; ++j)                                         \
            acc[i][j] = __builtin_amdgcn_mfma_f32_16x16x32_bf16(            \
                af[i], bfr[j], acc[i][j], 0, 0, 0);                         \
} while (0)

template<int EPI, typename OutT>
__global__ __launch_bounds__(256)
void mm_bf16(const ushort_t* __restrict__ A, long long sAb, int lda, int M,
             const ushort_t* __restrict__ B, long long sBb, int ldb, int Nv,
             const float* __restrict__ bias,
             OutT* __restrict__ O, long long sOb, int ldo,
             int K, float alpha,
             ushort_t* __restrict__ qQ, ushort_t* __restrict__ qK, ushort_t* __restrict__ qV)
{
    __shared__ __align__(16) ushort_t As0[128 * 32];
    __shared__ __align__(16) ushort_t As1[128 * 32];
    __shared__ __align__(16) ushort_t Bs0[128 * 32];
    __shared__ __align__(16) ushort_t Bs1[128 * 32];
    const int z = blockIdx.z;
    A += (long long)z * sAb; B += (long long)z * sBb;
    if (O) O += (long long)z * sOb;
    const int n0 = blockIdx.x * 128;
    const int m0 = blockIdx.y * 128;
    const int tid = threadIdx.x;
    const int lane = tid & 63;
    const int wv = tid >> 6;
    const int wr = (wv >> 1) << 6;
    const int wc = (wv & 1) << 6;
    const int fr = lane & 15;
    const int kq = lane >> 4;

    const int e0 = tid * 8, e1 = 2048 + tid * 8;
    const int ra0 = e0 >> 5, qa0 = (((e0 & 31) >> 3) ^ (ra0 & 3)) << 3;
    const int ra1 = e1 >> 5, qa1 = (((e1 & 31) >> 3) ^ (ra1 & 3)) << 3;
    const ushort_t* Ag0 = A + (long long)min(m0 + ra0, M - 1) * lda + qa0;
    const ushort_t* Ag1 = A + (long long)min(m0 + ra1, M - 1) * lda + qa1;
    const ushort_t* Bg0 = B + (long long)min(n0 + ra0, Nv - 1) * ldb + qa0;
    const ushort_t* Bg1 = B + (long long)min(n0 + ra1, Nv - 1) * ldb + qa1;

    f32x4 acc[4][4] = {};
    const int nt = K >> 5;

    MM_STAGE(As0, Bs0, 0);
    __syncthreads();

    for (int t = 0; t < nt; t += 2) {
        MM_STAGE(As1, Bs1, (t + 1) << 5);
        MM_COMPUTE(As0, Bs0);
        __syncthreads();
        if (t + 2 < nt) MM_STAGE(As0, Bs0, (t + 2) << 5);
        MM_COMPUTE(As1, Bs1);
        __syncthreads();
    }

    #pragma unroll
    for (int i = 0; i < 4; ++i) {
        int mb = m0 + wr + i * 16 + (lane >> 4) * 4;
        #pragma unroll
        for (int j = 0; j < 4; ++j) {
            int n = n0 + wc + j * 16 + fr;
            if (n >= Nv) continue;
            f32x4 v4 = acc[i][j];
            #pragma unroll
            for (int r = 0; r < 4; ++r) {
                int m = mb + r;
                if (m >= M) continue;
                float v = v4[r] * alpha;
                if constexpr (EPI == EPS_QKV) {
                    int b_l = m / Nn_, rr = m - b_l * Nn_;
                    if (n < Cc)            qQ[(long long)m * Cc + n] = f2b(v);
                    else if (n < 2 * Cc)   qK[(long long)m * Cc + (n - Cc)] = f2b(v);
                    else                   qV[((long long)b_l * Cc + (n - 2 * Cc)) * Np + rr] = f2b(v);
                } else if constexpr (EPI == EPS_ADD) {
                    if (bias) v += bias[n];
                    long long oi = (long long)m * ldo + n;
                    O[oi] += v;
                } else {
                    if (bias) v += bias[n];
                    if constexpr (EPI == EPS_X2) v *= 2.f;
                    if constexpr (EPI == EPS_GELU) v = gelu_f(v);
                    long long oi = (long long)m * ldo + n;
                    if constexpr (sizeof(OutT) == 2) O[oi] = (OutT)f2b(v);
                    else                             O[oi] = (OutT)v;
                }
            }
        }
    }
}

// =====================================================================
// 256x256 / BK=64 / 8-wave 8-phase GEMM (m201 template port).
// Half-tiles = K-slices: per K-tile t, 4 halves {A-ks0, B-ks0, A-ks1, B-ks1},
// each 256 rows x 32 k bf16 = 16KB, double-buffered -> 128KB LDS.
// LDS layout per half: 16B chunk (row r, c in 0..3) at slot
//   line*8 + ((c + 4*(r&1)) ^ (line&7)), line = r>>1   (conflict-free ds_read,
//   involution applied on the global-source side; gl16 writes linearly).
// Per phase: {ds_read 4-8 b128 | stage 1 half of tile t+1 (2 gl16) |
//   counted vmcnt(4) at phases 1,3 only | barrier | lgkmcnt(0)+sched_barrier |
//   setprio(1) 16 MFMA setprio(0) | barrier}.
// Wait chain: half staged at (t,phX) is first read >= 2 phases + 2 barriers
// later; vmcnt(4) at (t,ph1) publishes (t,ks1)-halves, at (t,ph3) publishes
// (t+1,ks0)-halves. WAR distance on a buffer = 4 phases. Never vmcnt(0)
// mid-loop (only in the tail tile).
// =====================================================================
#define STAGE8(P, h, tt) do {                                        \
    const int ko_ = (tt) * 64 + ((h) >> 1) * 32;                     \
    if (((h) & 1) == 0) {                                            \
        gl16(AsS0 + ko_, &HA[P][(h) >> 1][s0 * 8]);                  \
        gl16(AsS1 + ko_, &HA[P][(h) >> 1][s1 * 8]);                  \
    } else {                                                         \
        gl16(BsS0 + ko_, &HB[P][(h) >> 1][s0 * 8]);                  \
        gl16(BsS1 + ko_, &HB[P][(h) >> 1][s1 * 8]);                  \
    }                                                                \
} while (0)

#define LDA4(P, ks, fbase) do {                                      \
    _Pragma("unroll")                                                \
    for (int f_ = 0; f_ < 4; ++f_)                                   \
        av[f_] = *(const short8*)&HA[P][ks][abase + ((fbase) + f_) * 512]; \
} while (0)

#define LDB4(P, ks) do {                                             \
    _Pragma("unroll")                                                \
    for (int n_ = 0; n_ < 4; ++n_)                                   \
        bv[n_] = *(const short8*)&HB[P][ks][bbase + n_ * 512];       \
} while (0)

#define MFMA16(fbase) do {                                           \
    __builtin_amdgcn_s_setprio(1);                                   \
    _Pragma("unroll")                                                \
    for (int f_ = 0; f_ < 4; ++f_)                                   \
        _Pragma("unroll")                                            \
        for (int n_ = 0; n_ < 4; ++n_)                               \
            acc[(fbase) + f_][n_] = __builtin_amdgcn_mfma_f32_16x16x32_bf16( \
                av[f_], bv[n_], acc[(fbase) + f_][n_], 0, 0, 0);     \
    __builtin_amdgcn_s_setprio(0);                                   \
} while (0)

#define PH_SYNC() do {                                               \
    __builtin_amdgcn_s_barrier();                                    \
    asm volatile("s_waitcnt lgkmcnt(0)" ::: "memory");               \
    __builtin_amdgcn_sched_barrier(0);                               \
} while (0)

template<int EPI, typename OutT>
__global__ __launch_bounds__(512, 1)
void mm256(const ushort_t* __restrict__ A, int lda, int M,
           const ushort_t* __restrict__ B, int ldb, int Nv,
           const float* __restrict__ bias,
           OutT* __restrict__ O, int ldo,
           int K, float alpha,
           ushort_t* __restrict__ qQ, ushort_t* __restrict__ qK, ushort_t* __restrict__ qV)
{
    __shared__ __align__(16) ushort_t HA[2][2][8192];   // [dbuf][kslice] 16KB each
    __shared__ __align__(16) ushort_t HB[2][2][8192];

    // T1: bijective XCD-aware remap (m204 formula)
    const int nwg = gridDim.x * gridDim.y;
    const int flat = blockIdx.y * gridDim.x + blockIdx.x;
    const int qq = nwg >> 3, rr8 = nwg & 7;
    const int xcd = flat & 7, idx = flat >> 3;
    const int wg = (xcd < rr8 ? xcd * (qq + 1) : rr8 * (qq + 1) + (xcd - rr8) * qq) + idx;
    const int bx = wg % gridDim.x, by = wg / gridDim.x;

    const int n0 = bx * 256, m0 = by * 256;
    const int tid = (int)threadIdx.x;
    const int lane = tid & 63;
    const int wv = tid >> 6;            // 0..7
    const int wm128 = (wv >> 2) * 128;  // wave M-half
    const int wn64  = (wv & 3) * 64;    // wave N-quarter
    const int fr = lane & 15;
    const int kq = lane >> 4;           // 16B chunk within 32-k slice

    // ds_read lane constants: slot-in-line = (kq + 4*(fr&1)) ^ (fr>>1)
    const int sl    = (kq + 4 * (fr & 1)) ^ (fr >> 1);
    const int lref  = (fr >> 1) * 64 + sl * 8;          // ushort offset
    const int abase = wm128 * 32 + lref;
    const int bbase = wn64 * 32 + lref;

    // staging: thread covers physical slots s0=tid, s1=tid+512 of each half.
    // inverse map: line = s>>3, u = (s&7)^(line&7), row = (line<<1)|(u>>2), c = u&3.
    const int s0 = tid, s1 = tid + 512;
    const int line0 = tid >> 3;
    const int u0 = (tid & 7) ^ (line0 & 7);
    const int r0 = (line0 << 1) | (u0 >> 2);
    const int c0 = u0 & 3;                 // slot s1 maps to row r0+128, same c0
    const ushort_t* AsS0 = A + (long long)min(m0 + r0,       M - 1) * lda + c0 * 8;
    const ushort_t* AsS1 = A + (long long)min(m0 + r0 + 128, M - 1) * lda + c0 * 8;
    const ushort_t* BsS0 = B + (long long)min(n0 + r0,       Nv - 1) * ldb + c0 * 8;
    const ushort_t* BsS1 = B + (long long)min(n0 + r0 + 128, Nv - 1) * ldb + c0 * 8;

    f32x4 acc[8][4] = {};
    const int nt = K >> 6;              // K % 64 == 0 at all call sites

    // prologue: stage all 4 halves of tile 0; publish ks0 halves
    STAGE8(0, 0, 0); STAGE8(0, 1, 0); STAGE8(0, 2, 0); STAGE8(0, 3, 0);
    asm volatile("s_waitcnt vmcnt(4)" ::: "memory");
    __builtin_amdgcn_s_barrier();

    for (int t = 0; t < nt; ++t) {
        const int P = t & 1, Q = P ^ 1;
        const bool pf = (t + 1 < nt);
        short8 av[4], bv[4];

        // phase 0: ks0, C-rows f0-3 (+B ks0); stage A-ks0 of t+1
        LDA4(P, 0, 0); LDB4(P, 0);
        if (pf) STAGE8(Q, 0, t + 1);
        PH_SYNC();
        MFMA16(0);
        __builtin_amdgcn_s_barrier();

        // phase 1: ks0, C-rows f4-7 (B reused); stage B-ks0 of t+1; vmcnt -> ks1 halves of t published
        LDA4(P, 0, 4);
        if (pf) { STAGE8(Q, 1, t + 1); asm volatile("s_waitcnt vmcnt(4)" ::: "memory"); }
        else    {                      asm volatile("s_waitcnt vmcnt(0)" ::: "memory"); }
        PH_SYNC();
        MFMA16(4);
        __builtin_amdgcn_s_barrier();

        // phase 2: ks1, C-rows f0-3 (+B ks1); stage A-ks1 of t+1
        LDA4(P, 1, 0); LDB4(P, 1);
        if (pf) STAGE8(Q, 2, t + 1);
        PH_SYNC();
        MFMA16(0);
        __builtin_amdgcn_s_barrier();

        // phase 3: ks1, C-rows f4-7; stage B-ks1 of t+1; vmcnt -> ks0 halves of t+1 published
        LDA4(P, 1, 4);
        if (pf) { STAGE8(Q, 3, t + 1); asm volatile("s_waitcnt vmcnt(4)" ::: "memory"); }
        PH_SYNC();
        MFMA16(4);
        __builtin_amdgcn_s_barrier();
    }

    // epilogue: m = m0 + wm128 + mf*16 + (lane>>4)*4 + r ; n = n0 + wn64 + nf*16 + fr
    #pragma unroll
    for (int mf = 0; mf < 8; ++mf) {
        int mb = m0 + wm128 + mf * 16 + (lane >> 4) * 4;
        #pragma unroll
        for (int nf = 0; nf < 4; ++nf) {
            int n = n0 + wn64 + nf * 16 + fr;
            if (n >= Nv) continue;
            f32x4 v4 = acc[mf][nf];
            #pragma unroll
            for (int r = 0; r < 4; ++r) {
                int m = mb + r;
                if (m >= M) continue;
                float v = v4[r] * alpha;
                if constexpr (EPI == EPS_QKV) {
                    int b_l = m / Nn_, rq = m - b_l * Nn_;
                    if (n < Cc)            qQ[(long long)m * Cc + n] = f2b(v);
                    else if (n < 2 * Cc)   qK[(long long)m * Cc + (n - Cc)] = f2b(v);
                    else                   qV[((long long)b_l * Cc + (n - 2 * Cc)) * Np + rq] = f2b(v);
                } else if constexpr (EPI == EPS_ADD) {
                    if (bias) v += bias[n];
                    long long oi = (long long)m * ldo + n;
                    O[oi] += v;          // single owner per output
                } else {
                    if (bias) v += bias[n];
                    if constexpr (EPI == EPS_X2) v *= 2.f;
                    if constexpr (EPI == EPS_GELU) v = gelu_f(v);
                    long long oi = (long long)m * ldo + n;
                    if constexpr (sizeof(OutT) == 2) O[oi] = (OutT)f2b(v);
                    else                             O[oi] = (OutT)v;
                }
            }
        }
    }
}

// ---------------- launcher ----------------
extern "C" void kernel_launch(void* const* d_in, const int* in_sizes, int n_in,
                              void* d_out, int out_size, void* d_ws, size_t ws_size,
                              hipStream_t stream) {
    const float* x      = (const float*)d_in[0];
    const float* n1w    = (const float*)d_in[1];
    const float* n1b    = (const float*)d_in[2];
    const float* qkv_w  = (const float*)d_in[3];
    const float* proj_w = (const float*)d_in[4];
    const float* proj_b = (const float*)d_in[5];
    const float* n2w    = (const float*)d_in[6];
    const float* n2b    = (const float*)d_in[7];
    const float* fc1w   = (const float*)d_in[8];
    const float* fc1b   = (const float*)d_in[9];
    const float* fc2w   = (const float*)d_in[10];
    const float* fc2b   = (const float*)d_in[11];
    float* out = (float*)d_out;
    float* x2  = out;
    float* tok = out + OUT_X;

    // ---- persistent bf16 weights at ws start ----
    char* ws = (char*)d_ws;
    const long long nWq = (long long)3 * Cc * Cc;
    const long long nWp = (long long)Cc * Cc;
    const long long nW1 = (long long)Hh * Cc;
    const long long nW2 = (long long)Cc * Hh;
    ushort_t* wq = (ushort_t*)ws;
    ushort_t* wp = wq + nWq;
    ushort_t* w1 = wp + nWp;
    ushort_t* w2 = w1 + nW1;
    const long long WBYTES = 2 * (nWq + nWp + nW1 + nW2); // 14,155,776
    char* dyn = ws + WBYTES;
    long long avail = (long long)ws_size - WBYTES;

    // ---- adaptive sizes (prefer no chunking: G=32, CH=full) ----
    const long long perG = 3LL * Nn_ * Cc * 2 + (long long)Cc * Np * 2
                         + (long long)Nn_ * Np * 4 + (long long)Nn_ * Np * 2;
    int G = 1;
    { const int o[6] = {32, 16, 8, 4, 2, 1};
      for (int i = 0; i < 6; ++i) if ((long long)o[i] * perG <= avail) { G = o[i]; break; } }
    int CH = Nn_;
    { const int o[6] = {32, 16, 8, 4, 2, 1};
      for (int i = 0; i < 6; ++i) if ((long long)o[i] * Nn_ * (Cc + Hh) * 2 <= avail) { CH = o[i] * Nn_; break; } }

    // phase A layout: hbf/Yt | Q | Kb | Vt | Sf | Sb
    ushort_t* hbf = (ushort_t*)dyn;
    ushort_t* Q   = hbf + (long long)G * Nn_ * Cc;
    ushort_t* Kb  = Q   + (long long)G * Nn_ * Cc;
    ushort_t* Vt  = Kb  + (long long)G * Nn_ * Cc;
    float*    Sf  = (float*)(Vt + (long long)G * Cc * Np);
    ushort_t* Sb  = (ushort_t*)(Sf + (long long)G * Nn_ * Np);
    ushort_t* Yt  = hbf;
    // phase B layout: g | t
    ushort_t* g = (ushort_t*)dyn;
    ushort_t* t = g + (long long)CH * Cc;

    // ---- weight conversion (every call; ws is re-poisoned) ----
    cvt_kernel<<<(int)((nWq + 255) / 256), 256, 0, stream>>>(qkv_w, wq, (int)nWq);
    cvt_kernel<<<(int)((nWp + 255) / 256), 256, 0, stream>>>(proj_w, wp, (int)nWp);
    cvt_kernel<<<(int)((nW1 + 255) / 256), 256, 0, stream>>>(fc1w, w1, (int)nW1);
    cvt_kernel<<<(int)((nW2 + 255) / 256), 256, 0, stream>>>(fc2w, w2, (int)nW2);

    // ================= phase A: attention per group of G batches =================
    for (int b0 = 0; b0 < Bz; b0 += G) {
        const int MR = G * Nn_;
        const int myM256 = (MR + 255) / 256;

        ln_bf16<<<MR, 256, 0, stream>>>(x + (long long)b0 * Nn_ * Cc, n1w, n1b, hbf);

        // qkv: (MR x 2304 x 768), scatter to Q | Kb | Vt  (8-phase 256-tile)
        mm256<EPS_QKV, float><<<dim3(9, myM256, 1), 512, 0, stream>>>(
            hbf, Cc, MR, wq, Cc, 3 * Cc, nullptr,
            (float*)nullptr, Cc, Cc, 1.f, Q, Kb, Vt);

        // Sf = scale * Q @ K^T per batch (577x577 valid, ld 640) — 128-tile batched
        mm_bf16<EPS_STORE, float><<<dim3(5, 5, G), 256, 0, stream>>>(
            Q, (long long)Nn_ * Cc, Cc, Nn_, Kb, (long long)Nn_ * Cc, Cc, Nn_, nullptr,
            Sf, (long long)Nn_ * Np, Np, Cc, SCALE, nullptr, nullptr, nullptr);

        softmax_bf16<<<MR, 256, 0, stream>>>(Sf, Sb, tok + (long long)b0 * 576);

        // Yt[c, n] = sum_m Vt[c, m] * Sb[n, m]  (M=768, N=577 valid, K=640) — 128-tile batched
        mm_bf16<EPS_STORE, ushort_t><<<dim3(5, 6, G), 256, 0, stream>>>(
            Vt, (long long)Cc * Np, Np, Cc, Sb, (long long)Nn_ * Np, Np, Nn_, nullptr,
            Yt, (long long)Cc * Nn_, Nn_, Np, 1.f, nullptr, nullptr, nullptr);

        // x2 = 2*(Yt_flat @ proj_w^T + proj_b) -> d_out rows of group (fp32)
        mm256<EPS_X2, float><<<dim3(3, myM256, 1), 512, 0, stream>>>(
            Yt, Cc, MR, wp, Cc, Cc, proj_b,
            x2 + (long long)b0 * Nn_ * Cc, Cc, Cc, 1.f, nullptr, nullptr, nullptr);
    }

    // ================= phase B: MLP per chunk of CH rows =================
    for (int c0 = 0; c0 < Mrows; c0 += CH) {
        const int cn = (Mrows - c0 < CH) ? (Mrows - c0) : CH;
        const int myC256 = (cn + 255) / 256;

        ln_bf16<<<cn, 256, 0, stream>>>(x2 + (long long)c0 * Cc, n2w, n2b, g);

        // t = gelu(g @ fc1^T + b1)  (cn x 3072 x 768), bf16
        mm256<EPS_GELU, ushort_t><<<dim3(12, myC256, 1), 512, 0, stream>>>(
            g, Cc, cn, w1, Cc, Hh, fc1b,
            t, Hh, Cc, 1.f, nullptr, nullptr, nullptr);

        // x2 += t @ fc2^T + b2  (cn x 768 x 3072), plain += epilogue
        mm256<EPS_ADD, float><<<dim3(3, myC256, 1), 512, 0, stream>>>(
            t, Hh, cn, w2, Hh, Cc, fc2b,
            x2 + (long long)c0 * Cc, Cc, Hh, 1.f, nullptr, nullptr, nullptr);
    }
}